// Round 3
// baseline (50.428 us; speedup 1.0000x reference)
//
#include <hip/hip_runtime.h>

// GraphConvLayer on MI355X (gfx950). ALL device tensors are FLOAT32
// (adjacency int32); output float32. bf16 used only inside MFMA.
//
// Algebra: softmax_j(src_i + dst_j + b_att) over neighbors == e_j / sum_j e_j
// (src_i, b_att constant along j -> cancel; a_src, b_att unused).
//   Z[:, b*64+f]   = A @ (e .* X[b])        (one shared GEMM over all batches)
//   Z[:, 4096+b]   = A @ e[b]               (denominator columns)
//   out = relu(LN(X@Ws^T + bs + (Z_b@Wn^T)/den + bn[den>0]))

typedef unsigned short u16;
typedef unsigned int u32;
typedef short bf16x8 __attribute__((ext_vector_type(8)));
typedef float f32x4 __attribute__((ext_vector_type(4)));

#define NNODE 784
#define MP 832            // padded node count (K of big GEMM)
#define NP 4160           // 64 batches * 64 feats + 64 denom columns
#define LDP 72            // bf16 LDS row pitch (144 B)

__device__ __forceinline__ u16 f2b(float f) {
  union { float f; u32 u; } v; v.f = f;
  u32 r = (v.u + 0x7FFFu + ((v.u >> 16) & 1u)) >> 16;
  return (u16)r;
}

// convert 16 consecutive f32 -> 16 bf16 into LDS (dst 16B-aligned)
__device__ __forceinline__ void cvt16(u16* dst, const float4* src) {
  float4 v0 = src[0], v1 = src[1], v2 = src[2], v3 = src[3];
  __align__(16) u16 ob[16];
  ob[0] = f2b(v0.x);  ob[1] = f2b(v0.y);  ob[2] = f2b(v0.z);  ob[3] = f2b(v0.w);
  ob[4] = f2b(v1.x);  ob[5] = f2b(v1.y);  ob[6] = f2b(v1.z);  ob[7] = f2b(v1.w);
  ob[8] = f2b(v2.x);  ob[9] = f2b(v2.y);  ob[10] = f2b(v2.z); ob[11] = f2b(v2.w);
  ob[12] = f2b(v3.x); ob[13] = f2b(v3.y); ob[14] = f2b(v3.z); ob[15] = f2b(v3.w);
  *(uint4*)dst = *(const uint4*)ob;
  *(uint4*)(dst + 8) = *(const uint4*)(ob + 8);
}

// ---------- K1: e[r] = exp(x_r . a_dst); 8 lanes per row ----------
__global__ __launch_bounds__(256) void k_e(const float* __restrict__ X,
                                           const float* __restrict__ adst,
                                           float* __restrict__ e) {
  int tid = threadIdx.x;
  int r = blockIdx.x * 32 + (tid >> 3);
  int p = tid & 7;
  const float4* xp = (const float4*)(X + (size_t)r * 64 + p * 8);
  const float4* ap = (const float4*)(adst + p * 8);
  float4 x0 = xp[0], x1 = xp[1];
  float4 a0 = ap[0], a1 = ap[1];
  float acc = x0.x * a0.x + x0.y * a0.y + x0.z * a0.z + x0.w * a0.w
            + x1.x * a1.x + x1.y * a1.y + x1.z * a1.z + x1.w * a1.w;
  acc += __shfl_xor(acc, 1);
  acc += __shfl_xor(acc, 2);
  acc += __shfl_xor(acc, 4);
  if (p == 0) e[r] = __expf(acc);
}

// ---------- K2: adjacency int32 -> bf16 0/1, zero-padded to 832x832 ----------
__global__ __launch_bounds__(256) void k_amat(const int* __restrict__ adj,
                                              u16* __restrict__ A) {
  int idx = blockIdx.x * 256 + threadIdx.x;   // 832*832 threads exactly
  int i = idx / MP, j = idx - i * MP;
  u16 v = 0;
  if (i < NNODE && j < NNODE && adj[i * NNODE + j] != 0) v = 0x3F80;  // bf16 1.0
  A[idx] = v;
}

// ---------- K3: B1t[n][k]: n=b*64+f -> bf16(e_bj * X[b,j,f]); n=4096+b -> bf16(e_bj) ----------
__global__ __launch_bounds__(256) void k_b1t(const float* __restrict__ X,
                                             const float* __restrict__ e,
                                             u16* __restrict__ B1t) {
  __shared__ float Xs[64][68];   // pitch 68: 16B-aligned rows
  __shared__ float es[64];
  int b = blockIdx.x / 13, jt = blockIdx.x - b * 13;
  int j0 = jt * 64;
  int t = threadIdx.x;
  {
    int jr = t >> 2, cg = t & 3;
    int j = j0 + jr;
    float4 z4; z4.x = 0.f; z4.y = 0.f; z4.z = 0.f; z4.w = 0.f;
    float4 v0 = z4, v1 = z4, v2 = z4, v3 = z4;
    if (j < NNODE) {
      const float4* xp = (const float4*)(X + (size_t)(b * NNODE + j) * 64 + cg * 16);
      v0 = xp[0]; v1 = xp[1]; v2 = xp[2]; v3 = xp[3];
    }
    float4* d = (float4*)&Xs[jr][cg * 16];
    d[0] = v0; d[1] = v1; d[2] = v2; d[3] = v3;
  }
  if (t < 64) {
    int j = j0 + t;
    es[t] = (j < NNODE) ? e[b * NNODE + j] : 0.f;
  }
  __syncthreads();
  {
    int f = t >> 2, jc = (t & 3) * 16;
    __align__(16) u16 ob[16];
#pragma unroll
    for (int q = 0; q < 16; ++q) ob[q] = f2b(es[jc + q] * Xs[jc + q][f]);
    u16* op = B1t + (size_t)(b * 64 + f) * MP + j0 + jc;
    *(uint4*)op = *(const uint4*)ob;
    *(uint4*)(op + 8) = *(const uint4*)(ob + 8);
  }
  if (t < 64) B1t[(size_t)(4096 + b) * MP + j0 + t] = f2b(es[t]);
}

// ---------- K4: Z[832][4160](f32) = A_pad @ B1t^T  (MFMA 16x16x32 bf16) ----------
__global__ __launch_bounds__(256) void k_gemm(const u16* __restrict__ A,
                                              const u16* __restrict__ Bt,
                                              float* __restrict__ Z) {
  __shared__ __align__(16) u16 As[64][LDP];
  __shared__ __align__(16) u16 Bs[64][LDP];
  const int tid = threadIdx.x;
  const int w = tid >> 6, l = tid & 63;
  const int n0 = blockIdx.x * 64, i0 = blockIdx.y * 64;
  const int rlo = tid >> 3, ch = tid & 7;
  const int g = l >> 4, l15 = l & 15;
  const int wr = w >> 1, wc = w & 1;
  f32x4 acc00 = {0.f, 0.f, 0.f, 0.f}, acc01 = {0.f, 0.f, 0.f, 0.f};
  f32x4 acc10 = {0.f, 0.f, 0.f, 0.f}, acc11 = {0.f, 0.f, 0.f, 0.f};

  for (int kt = 0; kt < 13; ++kt) {
    const int k0 = kt * 64;
#pragma unroll
    for (int c = 0; c < 2; ++c) {
      int row = rlo + c * 32;
      uint4 va = *(const uint4*)(A + (size_t)(i0 + row) * MP + k0 + ch * 8);
      uint4 vb = *(const uint4*)(Bt + (size_t)(n0 + row) * MP + k0 + ch * 8);
      *(uint4*)&As[row][ch * 8] = va;
      *(uint4*)&Bs[row][ch * 8] = vb;
    }
    __syncthreads();
    int r0a = 32 * wr + l15, r1a = r0a + 16;
    int c0b = 32 * wc + l15, c1b = c0b + 16;
#pragma unroll
    for (int kk = 0; kk < 2; ++kk) {
      int q = kk * 4 + g;
      bf16x8 a0 = *(const bf16x8*)&As[r0a][q * 8];
      bf16x8 a1 = *(const bf16x8*)&As[r1a][q * 8];
      bf16x8 b0 = *(const bf16x8*)&Bs[c0b][q * 8];
      bf16x8 b1 = *(const bf16x8*)&Bs[c1b][q * 8];
      acc00 = __builtin_amdgcn_mfma_f32_16x16x32_bf16(a0, b0, acc00, 0, 0, 0);
      acc01 = __builtin_amdgcn_mfma_f32_16x16x32_bf16(a0, b1, acc01, 0, 0, 0);
      acc10 = __builtin_amdgcn_mfma_f32_16x16x32_bf16(a1, b0, acc10, 0, 0, 0);
      acc11 = __builtin_amdgcn_mfma_f32_16x16x32_bf16(a1, b1, acc11, 0, 0, 0);
    }
    __syncthreads();
  }
  int colBase = n0 + 32 * wc + l15;
  int rowBase = i0 + 32 * wr + 4 * g;          // C/D: col=lane&15, row=(lane>>4)*4+reg
#pragma unroll
  for (int j = 0; j < 4; ++j) {
    Z[(size_t)(rowBase + j) * NP + colBase]           = acc00[j];
    Z[(size_t)(rowBase + j) * NP + colBase + 16]      = acc01[j];
    Z[(size_t)(rowBase + 16 + j) * NP + colBase]      = acc10[j];
    Z[(size_t)(rowBase + 16 + j) * NP + colBase + 16] = acc11[j];
  }
}

// ---------- K5: fused tail. 64 rows/block: S=X@Ws^T, G=Zb@Wn^T, LN, ReLU ----------
__global__ __launch_bounds__(256) void k_tail(const float* __restrict__ X,
                                              const float* __restrict__ Z,
                                              const float* __restrict__ Ws,
                                              const float* __restrict__ Wn,
                                              const float* __restrict__ bs,
                                              const float* __restrict__ bn,
                                              const float* __restrict__ gam,
                                              const float* __restrict__ bet,
                                              float* __restrict__ out) {
  __shared__ __align__(16) u16 Xs[64][LDP];
  __shared__ __align__(16) u16 Zs[64][LDP];
  __shared__ __align__(16) u16 WsS[64][LDP];
  __shared__ __align__(16) u16 WnS[64][LDP];
  __shared__ float comb[64][65];
  __shared__ float dens[64], bsL[64], bnL[64], gamL[64], betL[64];
  const int R0 = blockIdx.x * 64;
  const int t = threadIdx.x;
  {
    int rl = t >> 2, cg = t & 3;
    int R = R0 + rl;
    int bq = R / NNODE, i = R - bq * NNODE;
    cvt16(&Xs[rl][cg * 16],  (const float4*)(X + (size_t)R * 64 + cg * 16));
    cvt16(&Zs[rl][cg * 16],  (const float4*)(Z + (size_t)i * NP + bq * 64 + cg * 16));
    cvt16(&WsS[rl][cg * 16], (const float4*)(Ws + rl * 64 + cg * 16));
    cvt16(&WnS[rl][cg * 16], (const float4*)(Wn + rl * 64 + cg * 16));
  }
  if (t < 64) {
    int R = R0 + t;
    int bq = R / NNODE, i = R - bq * NNODE;
    dens[t] = Z[(size_t)i * NP + 4096 + bq];
    bsL[t] = bs[t]; bnL[t] = bn[t]; gamL[t] = gam[t]; betL[t] = bet[t];
  }
  __syncthreads();

  const int w = t >> 6, l = t & 63;
  const int g = l >> 4, l15 = l & 15;
  const int wr = w >> 1, wc = w & 1;
  const int ra0 = 32 * wr + l15, ra1 = ra0 + 16;
  const int cb0 = 32 * wc + l15, cb1 = cb0 + 16;
  f32x4 s00 = {0.f,0.f,0.f,0.f}, s01 = s00, s10 = s00, s11 = s00;
  f32x4 g00 = s00, g01 = s00, g10 = s00, g11 = s00;
#pragma unroll
  for (int kk = 0; kk < 2; ++kk) {
    int q = kk * 4 + g;
    bf16x8 xa0 = *(const bf16x8*)&Xs[ra0][q * 8];
    bf16x8 xa1 = *(const bf16x8*)&Xs[ra1][q * 8];
    bf16x8 za0 = *(const bf16x8*)&Zs[ra0][q * 8];
    bf16x8 za1 = *(const bf16x8*)&Zs[ra1][q * 8];
    bf16x8 wb0 = *(const bf16x8*)&WsS[cb0][q * 8];
    bf16x8 wb1 = *(const bf16x8*)&WsS[cb1][q * 8];
    bf16x8 nb0 = *(const bf16x8*)&WnS[cb0][q * 8];
    bf16x8 nb1 = *(const bf16x8*)&WnS[cb1][q * 8];
    s00 = __builtin_amdgcn_mfma_f32_16x16x32_bf16(xa0, wb0, s00, 0, 0, 0);
    s01 = __builtin_amdgcn_mfma_f32_16x16x32_bf16(xa0, wb1, s01, 0, 0, 0);
    s10 = __builtin_amdgcn_mfma_f32_16x16x32_bf16(xa1, wb0, s10, 0, 0, 0);
    s11 = __builtin_amdgcn_mfma_f32_16x16x32_bf16(xa1, wb1, s11, 0, 0, 0);
    g00 = __builtin_amdgcn_mfma_f32_16x16x32_bf16(za0, nb0, g00, 0, 0, 0);
    g01 = __builtin_amdgcn_mfma_f32_16x16x32_bf16(za0, nb1, g01, 0, 0, 0);
    g10 = __builtin_amdgcn_mfma_f32_16x16x32_bf16(za1, nb0, g10, 0, 0, 0);
    g11 = __builtin_amdgcn_mfma_f32_16x16x32_bf16(za1, nb1, g11, 0, 0, 0);
  }
  {
    int rowB = 32 * wr + 4 * g;
    int colB = 32 * wc + l15;
#pragma unroll
    for (int j = 0; j < 4; ++j) {
      int r1 = rowB + j, r2 = r1 + 16;
      float d1 = dens[r1], d2 = dens[r2];
      float a00 = s00[j] + bsL[colB];
      float a01 = s01[j] + bsL[colB + 16];
      float a10 = s10[j] + bsL[colB];
      float a11 = s11[j] + bsL[colB + 16];
      if (d1 > 0.f) { a00 += g00[j] / d1 + bnL[colB]; a01 += g01[j] / d1 + bnL[colB + 16]; }
      if (d2 > 0.f) { a10 += g10[j] / d2 + bnL[colB]; a11 += g11[j] / d2 + bnL[colB + 16]; }
      comb[r1][colB]      = a00;
      comb[r1][colB + 16] = a01;
      comb[r2][colB]      = a10;
      comb[r2][colB + 16] = a11;
    }
  }
  __syncthreads();
  {
    int rl = t >> 2, c0 = (t & 3) * 16;
    float v[16];
    float s1 = 0.f, s2 = 0.f;
#pragma unroll
    for (int q = 0; q < 16; ++q) {
      v[q] = comb[rl][c0 + q];
      s1 += v[q];
      s2 += v[q] * v[q];
    }
    s1 += __shfl_xor(s1, 1); s1 += __shfl_xor(s1, 2);
    s2 += __shfl_xor(s2, 1); s2 += __shfl_xor(s2, 2);
    float mu = s1 * (1.f / 64.f);
    float var = s2 * (1.f / 64.f) - mu * mu;
    var = fmaxf(var, 0.f);
    float inv = rsqrtf(var + 1e-5f);
    int R = R0 + rl;
    float4* op = (float4*)(out + (size_t)R * 64 + c0);
#pragma unroll
    for (int qq = 0; qq < 4; ++qq) {
      float4 o;
      o.x = fmaxf((v[qq * 4 + 0] - mu) * inv * gamL[c0 + qq * 4 + 0] + betL[c0 + qq * 4 + 0], 0.f);
      o.y = fmaxf((v[qq * 4 + 1] - mu) * inv * gamL[c0 + qq * 4 + 1] + betL[c0 + qq * 4 + 1], 0.f);
      o.z = fmaxf((v[qq * 4 + 2] - mu) * inv * gamL[c0 + qq * 4 + 2] + betL[c0 + qq * 4 + 2], 0.f);
      o.w = fmaxf((v[qq * 4 + 3] - mu) * inv * gamL[c0 + qq * 4 + 3] + betL[c0 + qq * 4 + 3], 0.f);
      op[qq] = o;
    }
  }
}

extern "C" void kernel_launch(void* const* d_in, const int* in_sizes, int n_in,
                              void* d_out, int out_size, void* d_ws, size_t ws_size,
                              hipStream_t stream) {
  const float* X     = (const float*)d_in[0];
  const int*   adj   = (const int*)d_in[1];
  const float* Wself = (const float*)d_in[2];
  const float* bself = (const float*)d_in[3];
  const float* Wnb   = (const float*)d_in[4];
  const float* bnb   = (const float*)d_in[5];
  // d_in[6] = a_src : cancels in softmax (constant along j) -> unused
  const float* adst  = (const float*)d_in[7];
  // d_in[8] = b_att : cancels in softmax -> unused
  const float* gam   = (const float*)d_in[9];
  const float* bet   = (const float*)d_in[10];
  float* out = (float*)d_out;
  char* ws = (char*)d_ws;

  float* e  = (float*)(ws);                 // 50176 f32          =   200704 B
  u16* Apad = (u16*)(ws + 200704);          // 832*832 bf16       =  1384448 B
  u16* B1t  = (u16*)(ws + 1585152);         // 4160*832 bf16      =  6922240 B
  float* Zb = (float*)(ws + 8507392);       // 832*4160 f32       = 13844480 B (end 22351872)

  k_e   <<<dim3(1568),   dim3(256), 0, stream>>>(X, adst, e);
  k_amat<<<dim3(2704),   dim3(256), 0, stream>>>(adj, Apad);
  k_b1t <<<dim3(832),    dim3(256), 0, stream>>>(X, e, B1t);
  k_gemm<<<dim3(65, 13), dim3(256), 0, stream>>>(Apad, B1t, Zb);
  k_tail<<<dim3(784),    dim3(256), 0, stream>>>(X, Zb, Wself, Wnb, bself, bnb, gam, bet, out);
}